// Round 10
// baseline (962.169 us; speedup 1.0000x reference)
//
#include <hip/hip_runtime.h>

#define NN 256
#define TT 512
#define BB 1024
#define DTC 0.01f

typedef _Float16 half8 __attribute__((ext_vector_type(8)));
typedef float f32x4 __attribute__((ext_vector_type(4)));
typedef float f32x2 __attribute__((ext_vector_type(2)));

// asm volatile MFMAs: "a" pins W in AGPRs; volatile = fixed issue order.
// HAZARD RULE (R8): MFMA-dest -> VALU-read has no hw interlock; tie each
// acc group with volatile asm (+s_nop spacing if unshadowed) before reads.
__device__ __forceinline__ f32x4 mfma_z(half8 a, half8 b) {
  f32x4 d;
  asm volatile("v_mfma_f32_16x16x32_f16 %0, %1, %2, 0" : "=v"(d) : "a"(a), "v"(b));
  return d;
}
__device__ __forceinline__ void mfma_p(f32x4& c, half8 a, half8 b) {
  asm volatile("v_mfma_f32_16x16x32_f16 %0, %1, %2, %0" : "+v"(c) : "a"(a), "v"(b));
}

template <int CTRL>
__device__ __forceinline__ float rormax(float x) {
  int yi = __builtin_amdgcn_update_dpp(0, __float_as_int(x), CTRL, 0xf, 0xf, false);
  return fmaxf(x, __int_as_float(yi));
}

// 8 waves (2/SIMD), wave w owns neurons [32w,32w+32) = 2 tiles, 48 MFMAs.
// MFMA blocks its wave ~32cyc (R4-R9 evidence); 2 waves/SIMD interleave on
// the ~19cyc matrix pipe and hide each other's VALU/LDS. 3-deep rotating
// LDS read pipeline keeps live b-frags <=3 pairs so VGPR+AGPR fits 2/SIMD.
__global__ __launch_bounds__(512, 2) void ring_attractor_kernel(
    const float* __restrict__ W, const float* __restrict__ log_scale,
    const float* __restrict__ gain, const float* __restrict__ bias,
    const float* __restrict__ log_tau, const float* __restrict__ vscale_p,
    const float* __restrict__ lscale_p, const float* __restrict__ velocity,
    const float* __restrict__ landmarks, float* __restrict__ out) {
  __shared__ __align__(16) _Float16 fragH[2][4096];
  __shared__ __align__(16) _Float16 fragL[2][4096];
  __shared__ __align__(16) float maxslot[2][8];

  const int tid = threadIdx.x;
  const int w  = tid >> 6;   // 0..7
  const int l  = tid & 63;
  const int g  = l >> 4;
  const int li = l & 15;
  const int br = blockIdx.x * 16 + li;

  const float es  = expf(log_scale[0]);
  const float vs  = vscale_p[0];
  const float lms = lscale_p[0];

  float gain_r[2][4], bias_r[2][4], coef_r[2][4];
#pragma unroll
  for (int nt = 0; nt < 2; ++nt)
#pragma unroll
    for (int q = 0; q < 4; ++q) {
      int c = w * 32 + nt * 16 + g * 4 + q;
      gain_r[nt][q] = gain[c];
      bias_r[nt][q] = bias[c];
      coef_r[nt][q] = DTC / expf(log_tau[c]);
    }

  // Resident W_eff^T hi/lo (128 AGPRs). m = w*32+nt*16+li, k = 32ks+4g+(j&3)+16(j>>2)
  half8 whi[2][8], wlo[2][8];
#pragma unroll
  for (int nt = 0; nt < 2; ++nt)
#pragma unroll
    for (int ks = 0; ks < 8; ++ks) {
      half8 hi, lo;
#pragma unroll
      for (int j = 0; j < 8; ++j) {
        int k = ks * 32 + g * 4 + (j & 3) + ((j >> 2) << 4);
        int m = w * 32 + nt * 16 + li;
        float wv = W[k * NN + m] * es;
        _Float16 h = (_Float16)wv;
        hi[j] = h;
        lo[j] = (_Float16)(wv - (float)h);
      }
      whi[nt][ks] = hi;
      wlo[nt][ks] = lo;
    }

  float s_r[2][4];
#pragma unroll
  for (int nt = 0; nt < 2; ++nt)
#pragma unroll
    for (int q = 0; q < 4; ++q) s_r[nt][q] = 0.f;

  // Wave w's output half8 = exactly frag k-slice ks=w (k-32w = 16nt+4g+q <-> j=q+4nt)
  const int wb = (w * 64 + g * 16 + li) * 8;
  {
    half8 z;
#pragma unroll
    for (int j = 0; j < 8; ++j) z[j] = (_Float16)0.f;
    *reinterpret_cast<half8*>(&fragH[0][wb]) = z;
    *reinterpret_cast<half8*>(&fragL[0][wb]) = z;
    if (tid < 16) maxslot[tid >> 3][tid & 7] = 0.f;
  }
  float inv_scale = 1.f;
  float amPrev = 0.f;
  __syncthreads();

#define SB() __builtin_amdgcn_sched_barrier(0)

#define RD2(CUR, KS, BH, BL)                                                   \
  {                                                                            \
    const int rb = ((KS)*64 + g * 16 + li) * 8;                                \
    BH = *reinterpret_cast<const half8*>(&fragH[CUR][rb]);                     \
    BL = *reinterpret_cast<const half8*>(&fragL[CUR][rb]);                     \
  }

// 6-chain MFMA block for one k-slice (both tiles x {hh, lh, hl})
#define K6Z(BH, BL)                                                            \
  a0h = mfma_z(whi[0][0], BH);                                                 \
  a1h = mfma_z(whi[1][0], BH);                                                 \
  a0l = mfma_z(wlo[0][0], BH);                                                 \
  a1l = mfma_z(wlo[1][0], BH);                                                 \
  a0c = mfma_z(whi[0][0], BL);                                                 \
  a1c = mfma_z(whi[1][0], BL);
#define K6(KS, BH, BL)                                                         \
  mfma_p(a0h, whi[0][KS], BH);                                                 \
  mfma_p(a1h, whi[1][KS], BH);                                                 \
  mfma_p(a0l, wlo[0][KS], BH);                                                 \
  mfma_p(a1l, wlo[1][KS], BH);                                                 \
  mfma_p(a0c, whi[0][KS], BL);                                                 \
  mfma_p(a1c, whi[1][KS], BL);

#define TIEN(AH, AL, AC) \
  asm volatile("s_nop 7\n\ts_nop 7" : "+v"(AH), "+v"(AL), "+v"(AC))

// One output element of tile NT (same arithmetic order as R4 lineage).
#define TQ(NT, Q, AH, AL, AC)                                                  \
  {                                                                            \
    float av = AH[Q] + AL[Q] + AC[Q];                                          \
    float ext;                                                                 \
    if (w < 2)                                                                 \
      ext = lms * ((NT) ? lm1[Q] : lm0[Q]);                                    \
    else if (w == 2)                                                           \
      ext = vs * vv0;                                                          \
    else if (w == 3)                                                           \
      ext = vs * vv1;                                                          \
    else                                                                       \
      ext = 0.f;                                                               \
    float tot = __builtin_fmaf(av, inv_scale, ext);                            \
    float rate =                                                               \
        fmaxf(__builtin_fmaf(gain_r[NT][Q], tot, bias_r[NT][Q]), 0.f);         \
    float sv = s_r[NT][Q];                                                     \
    sv = __builtin_fmaf(coef_r[NT][Q], rate - sv, sv);                         \
    s_r[NT][Q] = sv;                                                           \
    am = fmaxf(am, fabsf(sv));                                                 \
  }

#define STEP(T, CUR)                                                           \
  {                                                                            \
    /* ext inputs; HBM latency hides under MFMA phase */                       \
    f32x4 lm0{}, lm1{};                                                        \
    float vv0 = 0.f, vv1 = 0.f;                                                \
    if (w < 2) {                                                               \
      const float* p = landmarks + ((size_t)(T)*BB + br) * 64 + w * 32 + g * 4;\
      lm0 = *reinterpret_cast<const f32x4*>(p);                                \
      lm1 = *reinterpret_cast<const f32x4*>(p + 16);                           \
    } else if (w < 4) {                                                        \
      f32x2 pv = *reinterpret_cast<const f32x2*>(velocity +                    \
                                                 ((size_t)(T)*BB + br) * 2);   \
      vv0 = pv[0];                                                             \
      vv1 = pv[1];                                                             \
    }                                                                          \
    /* M_{T-1} read + reduce prev step's max -> maxslot[CUR][w] */             \
    f32x4 mva = *reinterpret_cast<const f32x4*>(&maxslot[CUR ^ 1][0]);         \
    f32x4 mvb = *reinterpret_cast<const f32x4*>(&maxslot[CUR ^ 1][4]);         \
    {                                                                          \
      float r = amPrev;                                                        \
      r = rormax<0x121>(r);                                                    \
      r = rormax<0x122>(r);                                                    \
      r = rormax<0x124>(r);                                                    \
      r = rormax<0x128>(r);                                                    \
      r = fmaxf(r, __shfl_xor(r, 16));                                         \
      r = fmaxf(r, __shfl_xor(r, 32));                                         \
      if (l == 0) maxslot[CUR][w] = r;                                         \
    }                                                                          \
    float scale_n, inv_n;                                                      \
    {                                                                          \
      float M = fmaxf(fmaxf(fmaxf(mva[0], mva[1]), fmaxf(mva[2], mva[3])),     \
                      fmaxf(fmaxf(mvb[0], mvb[1]), fmaxf(mvb[2], mvb[3])));    \
      int e = 134 - (int)(__float_as_uint(M) >> 23);                           \
      e = e > 9 ? 9 : e;                                                       \
      scale_n = __int_as_float((e + 127) << 23);                               \
      inv_n = __int_as_float((127 - e) << 23);                                 \
    }                                                                          \
    /* 3-deep rotating read pipeline under the 48-MFMA stream */               \
    half8 bh0, bl0, bh1, bl1, bh2, bl2, bh3, bl3;                              \
    half8 bh4, bl4, bh5, bl5, bh6, bl6, bh7, bl7;                              \
    f32x4 a0h, a0l, a0c, a1h, a1l, a1c;                                        \
    RD2(CUR, 0, bh0, bl0)                                                      \
    RD2(CUR, 1, bh1, bl1)                                                      \
    SB();                                                                      \
    K6Z(bh0, bl0)                                                              \
    SB();                                                                      \
    RD2(CUR, 2, bh2, bl2)                                                      \
    SB();                                                                      \
    K6(1, bh1, bl1)                                                            \
    SB();                                                                      \
    RD2(CUR, 3, bh3, bl3)                                                      \
    SB();                                                                      \
    K6(2, bh2, bl2)                                                            \
    SB();                                                                      \
    RD2(CUR, 4, bh4, bl4)                                                      \
    SB();                                                                      \
    K6(3, bh3, bl3)                                                            \
    SB();                                                                      \
    RD2(CUR, 5, bh5, bl5)                                                      \
    SB();                                                                      \
    K6(4, bh4, bl4)                                                            \
    SB();                                                                      \
    RD2(CUR, 6, bh6, bl6)                                                      \
    SB();                                                                      \
    K6(5, bh5, bl5)                                                            \
    SB();                                                                      \
    RD2(CUR, 7, bh7, bl7)                                                      \
    SB();                                                                      \
    K6(6, bh6, bl6)                                                            \
    K6(7, bh7, bl7)                                                            \
    /* tails: other wave's MFMAs cover this VALU; hazard ties kept */          \
    float am = 0.f;                                                            \
    TIEN(a0h, a0l, a0c);                                                       \
    TQ(0, 0, a0h, a0l, a0c)                                                    \
    TQ(0, 1, a0h, a0l, a0c)                                                    \
    TQ(0, 2, a0h, a0l, a0c)                                                    \
    TQ(0, 3, a0h, a0l, a0c)                                                    \
    TIEN(a1h, a1l, a1c);                                                       \
    TQ(1, 0, a1h, a1l, a1c)                                                    \
    TQ(1, 1, a1h, a1l, a1c)                                                    \
    TQ(1, 2, a1h, a1l, a1c)                                                    \
    TQ(1, 3, a1h, a1l, a1c)                                                    \
    /* quantize s_{T+1} hi/lo -> own frag slot of next buffer */               \
    {                                                                          \
      half8 hq, lq;                                                            \
      _Pragma("unroll") for (int j = 0; j < 8; ++j) {                          \
        float sc = s_r[j >> 2][j & 3] * scale_n;                               \
        _Float16 qh = (_Float16)sc;                                            \
        hq[j] = qh;                                                            \
        lq[j] = (_Float16)(sc - (float)qh);                                    \
      }                                                                        \
      *reinterpret_cast<half8*>(&fragH[CUR ^ 1][wb]) = hq;                     \
      *reinterpret_cast<half8*>(&fragL[CUR ^ 1][wb]) = lq;                     \
    }                                                                          \
    amPrev = am;                                                               \
    inv_scale = inv_n;                                                         \
    __syncthreads();                                                           \
  }

#pragma unroll 1
  for (int t = 0; t < TT; t += 2) {
    STEP(t, 0)
    STEP(t + 1, 1)
  }
#undef STEP
#undef TQ
#undef TIEN
#undef K6
#undef K6Z
#undef RD2
#undef SB

  // Epilogue: epg output = neurons [0,64) -> waves 0,1
  if (w < 2) {
#pragma unroll
    for (int nt = 0; nt < 2; ++nt) {
      f32x4 o;
#pragma unroll
      for (int q = 0; q < 4; ++q) o[q] = s_r[nt][q];
      *reinterpret_cast<f32x4*>(out + (size_t)br * 64 + w * 32 + nt * 16 +
                                g * 4) = o;
    }
  }
}

extern "C" void kernel_launch(void* const* d_in, const int* in_sizes, int n_in,
                              void* d_out, int out_size, void* d_ws, size_t ws_size,
                              hipStream_t stream) {
  const float* W         = (const float*)d_in[0];
  const float* log_scale = (const float*)d_in[1];
  const float* gain      = (const float*)d_in[2];
  const float* bias      = (const float*)d_in[3];
  const float* log_tau   = (const float*)d_in[4];
  const float* vscale    = (const float*)d_in[5];
  const float* lscale    = (const float*)d_in[6];
  const float* velocity  = (const float*)d_in[7];
  const float* landmarks = (const float*)d_in[8];
  float* out = (float*)d_out;

  ring_attractor_kernel<<<dim3(BB / 16), dim3(512), 0, stream>>>(
      W, log_scale, gain, bias, log_tau, vscale, lscale, velocity, landmarks, out);
}

// Round 12
// 940.173 us; speedup vs baseline: 1.0234x; 1.0234x over previous
//
#include <hip/hip_runtime.h>

#define NN 256
#define TT 512
#define BB 1024
#define DTC 0.01f

typedef _Float16 half8 __attribute__((ext_vector_type(8)));
typedef float f32x4 __attribute__((ext_vector_type(4)));
typedef float f32x2 __attribute__((ext_vector_type(2)));

// max with lane rotated-by-CTRL within the 16-lane DPP row (VALU pipe, no LDS)
template <int CTRL>
__device__ __forceinline__ float rormax(float x) {
  int yi = __builtin_amdgcn_update_dpp(0, __float_as_int(x), CTRL, 0xf, 0xf, false);
  return fmaxf(x, __int_as_float(yi));
}

// 8 waves (2/SIMD target), wave w owns neurons [32w,32w+32) = 2 tiles.
// 3-TERM GEMM (R11 post-mortem: mandatory): (W_hi+W_lo)*s_hi + W_hi*s_lo.
// BUILTIN MFMAs with W in VGPRs: per-wave W = 128 regs (8-wave split), so
// W + accs + frags fit the 256-reg 2-wave/SIMD budget with slack for the
// compiler's lgkmcnt read pipelining and exact MFMA hazard handling —
// the configuration R3/R10 (AGPR+128-VGPR squeeze) never allowed.
__global__ __launch_bounds__(512, 2) void ring_attractor_kernel(
    const float* __restrict__ W, const float* __restrict__ log_scale,
    const float* __restrict__ gain, const float* __restrict__ bias,
    const float* __restrict__ log_tau, const float* __restrict__ vscale_p,
    const float* __restrict__ lscale_p, const float* __restrict__ velocity,
    const float* __restrict__ landmarks, float* __restrict__ out) {
  __shared__ __align__(16) _Float16 fragH[2][4096];
  __shared__ __align__(16) _Float16 fragL[2][4096];
  __shared__ __align__(16) float maxslot[2][8];

  const int tid = threadIdx.x;
  const int w  = tid >> 6;   // 0..7
  const int l  = tid & 63;
  const int g  = l >> 4;
  const int li = l & 15;
  const int br = blockIdx.x * 16 + li;

  const float es  = expf(log_scale[0]);
  const float vs  = vscale_p[0];
  const float lms = lscale_p[0];

  float gain_r[2][4], bias_r[2][4], coef_r[2][4];
#pragma unroll
  for (int nt = 0; nt < 2; ++nt)
#pragma unroll
    for (int q = 0; q < 4; ++q) {
      int c = w * 32 + nt * 16 + g * 4 + q;
      gain_r[nt][q] = gain[c];
      bias_r[nt][q] = bias[c];
      coef_r[nt][q] = DTC / expf(log_tau[c]);
    }

  // Resident W_eff^T hi/lo (128 VGPRs). m = w*32+nt*16+li, k = 32ks+4g+(j&3)+16(j>>2)
  half8 whi[2][8], wlo[2][8];
#pragma unroll
  for (int nt = 0; nt < 2; ++nt)
#pragma unroll
    for (int ks = 0; ks < 8; ++ks) {
      half8 hi, lo;
#pragma unroll
      for (int j = 0; j < 8; ++j) {
        int k = ks * 32 + g * 4 + (j & 3) + ((j >> 2) << 4);
        int m = w * 32 + nt * 16 + li;
        float wv = W[k * NN + m] * es;
        _Float16 h = (_Float16)wv;
        hi[j] = h;
        lo[j] = (_Float16)(wv - (float)h);
      }
      whi[nt][ks] = hi;
      wlo[nt][ks] = lo;
    }

  float s_r[2][4];
#pragma unroll
  for (int nt = 0; nt < 2; ++nt)
#pragma unroll
    for (int q = 0; q < 4; ++q) s_r[nt][q] = 0.f;

  // Wave w's 8 outputs = exactly frag k-slice ks=w (k-32w = 16nt+4g+q <-> j=q+4nt)
  const int wb = (w * 64 + g * 16 + li) * 8;
  {
    half8 z;
#pragma unroll
    for (int j = 0; j < 8; ++j) z[j] = (_Float16)0.f;
    *reinterpret_cast<half8*>(&fragH[0][wb]) = z;
    *reinterpret_cast<half8*>(&fragL[0][wb]) = z;
    if (tid < 16) maxslot[tid >> 3][tid & 7] = 0.f;
  }
  float inv_scale = 1.f;
  float amPrev = 0.f;
  __syncthreads();

#define MF(ACC, A, B) \
  ACC = __builtin_amdgcn_mfma_f32_16x16x32_f16((A), (B), ACC, 0, 0, 0)

#define STEP(T, CUR)                                                           \
  {                                                                            \
    /* ext inputs; HBM latency hides under MFMA phase */                       \
    f32x4 lm0{}, lm1{};                                                        \
    float vv0 = 0.f, vv1 = 0.f;                                                \
    if (w < 2) {                                                               \
      const float* p = landmarks + ((size_t)(T)*BB + br) * 64 + w * 32 + g * 4;\
      lm0 = *reinterpret_cast<const f32x4*>(p);                                \
      lm1 = *reinterpret_cast<const f32x4*>(p + 16);                           \
    } else if (w < 4) {                                                        \
      f32x2 pv = *reinterpret_cast<const f32x2*>(velocity +                    \
                                                 ((size_t)(T)*BB + br) * 2);   \
      vv0 = pv[0];                                                             \
      vv1 = pv[1];                                                             \
    }                                                                          \
    /* M_{T-1} read + reduce prev step's max -> maxslot[CUR][w] */             \
    f32x4 mva = *reinterpret_cast<const f32x4*>(&maxslot[CUR ^ 1][0]);         \
    f32x4 mvb = *reinterpret_cast<const f32x4*>(&maxslot[CUR ^ 1][4]);         \
    {                                                                          \
      float r = amPrev;                                                        \
      r = rormax<0x121>(r);                                                    \
      r = rormax<0x122>(r);                                                    \
      r = rormax<0x124>(r);                                                    \
      r = rormax<0x128>(r);                                                    \
      r = fmaxf(r, __shfl_xor(r, 16));                                         \
      r = fmaxf(r, __shfl_xor(r, 32));                                         \
      if (l == 0) maxslot[CUR][w] = r;                                         \
    }                                                                          \
    float scale_n, inv_n;                                                      \
    {                                                                          \
      float M = fmaxf(fmaxf(fmaxf(mva[0], mva[1]), fmaxf(mva[2], mva[3])),     \
                      fmaxf(fmaxf(mvb[0], mvb[1]), fmaxf(mvb[2], mvb[3])));    \
      int e = 134 - (int)(__float_as_uint(M) >> 23);                           \
      e = e > 9 ? 9 : e;                                                       \
      scale_n = __int_as_float((e + 127) << 23);                               \
      inv_n = __int_as_float((127 - e) << 23);                                 \
    }                                                                          \
    /* GEMM: 6 chains x 8 ks = 48 MFMA; compiler schedules reads/hazards */    \
    f32x4 a0h{}, a1h{}, a0l{}, a1l{}, a0c{}, a1c{};                            \
    _Pragma("unroll")                                                          \
    for (int ks = 0; ks < 8; ++ks) {                                           \
      const int rb = (ks * 64 + g * 16 + li) * 8;                              \
      half8 bh = *reinterpret_cast<const half8*>(&fragH[CUR][rb]);             \
      half8 bl = *reinterpret_cast<const half8*>(&fragL[CUR][rb]);             \
      MF(a0h, whi[0][ks], bh);                                                 \
      MF(a1h, whi[1][ks], bh);                                                 \
      MF(a0l, wlo[0][ks], bh);                                                 \
      MF(a1l, wlo[1][ks], bh);                                                 \
      MF(a0c, whi[0][ks], bl);                                                 \
      MF(a1c, whi[1][ks], bl);                                                 \
    }                                                                          \
    /* elementwise tails */                                                    \
    float am = 0.f;                                                            \
    _Pragma("unroll")                                                          \
    for (int nt = 0; nt < 2; ++nt) {                                           \
      f32x4 av = nt ? ((a1h + a1l) + a1c) : ((a0h + a0l) + a0c);               \
      _Pragma("unroll")                                                        \
      for (int q = 0; q < 4; ++q) {                                            \
        float ext;                                                             \
        if (w < 2)                                                             \
          ext = lms * (nt ? lm1[q] : lm0[q]);                                  \
        else if (w == 2)                                                       \
          ext = vs * vv0;                                                      \
        else if (w == 3)                                                       \
          ext = vs * vv1;                                                      \
        else                                                                   \
          ext = 0.f;                                                           \
        float tot = __builtin_fmaf(av[q], inv_scale, ext);                     \
        float rate = fmaxf(__builtin_fmaf(gain_r[nt][q], tot, bias_r[nt][q]),  \
                           0.f);                                               \
        float sv = s_r[nt][q];                                                 \
        sv = __builtin_fmaf(coef_r[nt][q], rate - sv, sv);                     \
        s_r[nt][q] = sv;                                                       \
        am = fmaxf(am, fabsf(sv));                                             \
      }                                                                        \
    }                                                                          \
    amPrev = am;                                                               \
    /* quantize s_{T+1} hi/lo -> own frag slot of next buffer */               \
    {                                                                          \
      half8 hq, lq;                                                            \
      _Pragma("unroll") for (int j = 0; j < 8; ++j) {                          \
        float sc = s_r[j >> 2][j & 3] * scale_n;                               \
        _Float16 qh = (_Float16)sc;                                            \
        hq[j] = qh;                                                            \
        lq[j] = (_Float16)(sc - (float)qh);                                    \
      }                                                                        \
      *reinterpret_cast<half8*>(&fragH[CUR ^ 1][wb]) = hq;                     \
      *reinterpret_cast<half8*>(&fragL[CUR ^ 1][wb]) = lq;                     \
    }                                                                          \
    inv_scale = inv_n;                                                         \
    __syncthreads();                                                           \
  }

#pragma unroll 1
  for (int t = 0; t < TT; t += 2) {
    STEP(t, 0)
    STEP(t + 1, 1)
  }
#undef STEP
#undef MF

  // Epilogue: epg output = neurons [0,64) -> waves 0,1
  if (w < 2) {
#pragma unroll
    for (int nt = 0; nt < 2; ++nt) {
      f32x4 o;
#pragma unroll
      for (int q = 0; q < 4; ++q) o[q] = s_r[nt][q];
      *reinterpret_cast<f32x4*>(out + (size_t)br * 64 + w * 32 + nt * 16 +
                                g * 4) = o;
    }
  }
}

extern "C" void kernel_launch(void* const* d_in, const int* in_sizes, int n_in,
                              void* d_out, int out_size, void* d_ws, size_t ws_size,
                              hipStream_t stream) {
  const float* W         = (const float*)d_in[0];
  const float* log_scale = (const float*)d_in[1];
  const float* gain      = (const float*)d_in[2];
  const float* bias      = (const float*)d_in[3];
  const float* log_tau   = (const float*)d_in[4];
  const float* vscale    = (const float*)d_in[5];
  const float* lscale    = (const float*)d_in[6];
  const float* velocity  = (const float*)d_in[7];
  const float* landmarks = (const float*)d_in[8];
  float* out = (float*)d_out;

  ring_attractor_kernel<<<dim3(BB / 16), dim3(512), 0, stream>>>(
      W, log_scale, gain, bias, log_tau, vscale, lscale, velocity, landmarks, out);
}

// Round 13
// 790.221 us; speedup vs baseline: 1.2176x; 1.1898x over previous
//
#include <hip/hip_runtime.h>

#define NN 256
#define TT 512
#define BB 1024
#define DTC 0.01f

typedef _Float16 half8 __attribute__((ext_vector_type(8)));
typedef float f32x4 __attribute__((ext_vector_type(4)));

// Canonical CDNA operand placement: A in AGPR (W resident), B in VGPR
// (LDS frags), C/D in AGPR (avoids solo-wave VGPR-dest writeback penalty —
// the R12 hypothesis). Non-volatile: compiler keeps scheduling freedom (R4).
__device__ __forceinline__ f32x4 mfma_z(half8 a, half8 b) {
  f32x4 d;
  asm("v_mfma_f32_16x16x32_f16 %0, %1, %2, 0" : "=a"(d) : "a"(a), "v"(b));
  return d;
}
__device__ __forceinline__ void mfma_p(f32x4& c, half8 a, half8 b) {
  asm("v_mfma_f32_16x16x32_f16 %0, %1, %2, %0" : "+a"(c) : "a"(a), "v"(b));
}

// max with lane rotated-by-CTRL within the 16-lane DPP row (VALU pipe, no LDS)
template <int CTRL>
__device__ __forceinline__ float rormax(float x) {
  int yi = __builtin_amdgcn_update_dpp(0, __float_as_int(x), CTRL, 0xf, 0xf, false);
  return fmaxf(x, __int_as_float(yi));
}

// One block = 16 batch rows, 4 waves, wave w owns neurons [64w,64w+64).
// GEMM transposed: D[m=neuron][n=batchrow] = W_eff^T * s^T, 3-term f16 hi/lo
// (mandatory per R11), W^T in 128 AGPRs + 48 AGPR accumulators.
__global__ __launch_bounds__(256, 1) void ring_attractor_kernel(
    const float* __restrict__ W, const float* __restrict__ log_scale,
    const float* __restrict__ gain, const float* __restrict__ bias,
    const float* __restrict__ log_tau, const float* __restrict__ vscale_p,
    const float* __restrict__ lscale_p, const float* __restrict__ velocity,
    const float* __restrict__ landmarks, float* __restrict__ out) {
  __shared__ __align__(16) _Float16 fragH[2][4096];
  __shared__ __align__(16) _Float16 fragL[2][4096];
  __shared__ __align__(16) float maxslot[2][4];

  const int tid = threadIdx.x;
  const int w  = tid >> 6;   // 0..3
  const int l  = tid & 63;
  const int g  = l >> 4;
  const int li = l & 15;
  const int br = blockIdx.x * 16 + li;

  const float es  = expf(log_scale[0]);
  const float vs  = vscale_p[0];
  const float lms = lscale_p[0];

  float gain_r[4][4], bias_r[4][4], coef_r[4][4];
#pragma unroll
  for (int nt = 0; nt < 4; ++nt)
#pragma unroll
    for (int q = 0; q < 4; ++q) {
      int c = w * 64 + nt * 16 + g * 4 + q;
      gain_r[nt][q] = gain[c];
      bias_r[nt][q] = bias[c];
      coef_r[nt][q] = DTC / expf(log_tau[c]);
    }

  // Resident W_eff^T hi/lo. A[m][k]: m = w*64+nt*16+li, k = 32ks+4g+(j&3)+16(j>>2)
  half8 whi[4][8], wlo[4][8];
#pragma unroll
  for (int nt = 0; nt < 4; ++nt)
#pragma unroll
    for (int ks = 0; ks < 8; ++ks) {
      half8 hi, lo;
#pragma unroll
      for (int j = 0; j < 8; ++j) {
        int k = ks * 32 + g * 4 + (j & 3) + ((j >> 2) << 4);
        int m = w * 64 + nt * 16 + li;
        float wv = W[k * NN + m] * es;
        _Float16 h = (_Float16)wv;
        hi[j] = h;
        lo[j] = (_Float16)(wv - (float)h);
      }
      whi[nt][ks] = hi;
      wlo[nt][ks] = lo;
    }

  float s_r[4][4];
#pragma unroll
  for (int nt = 0; nt < 4; ++nt)
#pragma unroll
    for (int q = 0; q < 4; ++q) s_r[nt][q] = 0.f;

  // Each lane owns 2 frag slots per buffer (k-slices ks = 2w, 2w+1)
  const int wb0 = ((w * 2 + 0) * 64 + g * 16 + li) * 8;
  const int wb1 = ((w * 2 + 1) * 64 + g * 16 + li) * 8;
  {
    half8 z;
#pragma unroll
    for (int j = 0; j < 8; ++j) z[j] = (_Float16)0.f;
    *reinterpret_cast<half8*>(&fragH[0][wb0]) = z;
    *reinterpret_cast<half8*>(&fragH[0][wb1]) = z;
    *reinterpret_cast<half8*>(&fragL[0][wb0]) = z;
    *reinterpret_cast<half8*>(&fragL[0][wb1]) = z;
    if (tid < 8) maxslot[tid >> 2][tid & 3] = 0.f;
  }
  float inv_scale = 1.f;
  float amPrev = 0.f;

  // Ext double-buffer: wave0 = 16 landmark floats; wave1 = v0,v1 in E0[0],E0[1]
  f32x4 eA0{}, eA1{}, eA2{}, eA3{}, eB0{}, eB1{}, eB2{}, eB3{};
  if (w == 0) {
    const float* p = landmarks + (size_t)br * 64 + g * 4;
    eA0 = *reinterpret_cast<const f32x4*>(p);
    eA1 = *reinterpret_cast<const f32x4*>(p + 16);
    eA2 = *reinterpret_cast<const f32x4*>(p + 32);
    eA3 = *reinterpret_cast<const f32x4*>(p + 48);
  } else if (w == 1) {
    const float* p = velocity + (size_t)br * 2;
    eA0[0] = p[0];
    eA0[1] = p[1];
  }
  __syncthreads();

#define STEP(T, CUR, E0, E1, E2, E3, P0, P1, P2, P3)                           \
  {                                                                            \
    /* (1) reduce prev step's per-lane max -> maxslot[CUR] (off crit path) */  \
    {                                                                          \
      float r = amPrev;                                                        \
      r = rormax<0x121>(r);                                                    \
      r = rormax<0x122>(r);                                                    \
      r = rormax<0x124>(r);                                                    \
      r = rormax<0x128>(r);                                                    \
      r = fmaxf(r, __shfl_xor(r, 16));                                         \
      r = fmaxf(r, __shfl_xor(r, 32));                                         \
      if (l == 0) maxslot[CUR][w] = r;                                         \
    }                                                                          \
    /* (2) M_{T-1} from other buffer (barrier-protected) */                    \
    float M;                                                                   \
    {                                                                          \
      f32x4 mv = *reinterpret_cast<const f32x4*>(&maxslot[CUR ^ 1][0]);        \
      M = fmaxf(fmaxf(mv[0], mv[1]), fmaxf(mv[2], mv[3]));                     \
    }                                                                          \
    /* (3) prefetch ext inputs for step T+1 */                                 \
    {                                                                          \
      const int tn = (T) + 1 < TT ? (T) + 1 : TT - 1;                          \
      if (w == 0) {                                                            \
        const float* p = landmarks + ((size_t)tn * BB + br) * 64 + g * 4;      \
        P0 = *reinterpret_cast<const f32x4*>(p);                               \
        P1 = *reinterpret_cast<const f32x4*>(p + 16);                          \
        P2 = *reinterpret_cast<const f32x4*>(p + 32);                          \
        P3 = *reinterpret_cast<const f32x4*>(p + 48);                          \
      } else if (w == 1) {                                                     \
        const float* p = velocity + ((size_t)tn * BB + br) * 2;                \
        P0[0] = p[0];                                                          \
        P0[1] = p[1];                                                          \
      }                                                                        \
    }                                                                          \
    /* (4) GEMM: 12 chains (4 tiles x {hh, lh, hl}), all-AGPR A and C/D */     \
    f32x4 a0h, a1h, a2h, a3h, a0l, a1l, a2l, a3l, a0c, a1c, a2c, a3c;          \
    _Pragma("unroll")                                                          \
    for (int ks = 0; ks < 8; ++ks) {                                           \
      const int rb = (ks * 64 + g * 16 + li) * 8;                              \
      half8 bh = *reinterpret_cast<const half8*>(&fragH[CUR][rb]);             \
      half8 bl = *reinterpret_cast<const half8*>(&fragL[CUR][rb]);             \
      if (ks == 0) {                                                           \
        a0h = mfma_z(whi[0][0], bh);                                           \
        a1h = mfma_z(whi[1][0], bh);                                           \
        a2h = mfma_z(whi[2][0], bh);                                           \
        a3h = mfma_z(whi[3][0], bh);                                           \
        a0l = mfma_z(wlo[0][0], bh);                                           \
        a1l = mfma_z(wlo[1][0], bh);                                           \
        a2l = mfma_z(wlo[2][0], bh);                                           \
        a3l = mfma_z(wlo[3][0], bh);                                           \
        a0c = mfma_z(whi[0][0], bl);                                           \
        a1c = mfma_z(whi[1][0], bl);                                           \
        a2c = mfma_z(whi[2][0], bl);                                           \
        a3c = mfma_z(whi[3][0], bl);                                           \
      } else {                                                                 \
        mfma_p(a0h, whi[0][ks], bh);                                           \
        mfma_p(a1h, whi[1][ks], bh);                                           \
        mfma_p(a2h, whi[2][ks], bh);                                           \
        mfma_p(a3h, whi[3][ks], bh);                                           \
        mfma_p(a0l, wlo[0][ks], bh);                                           \
        mfma_p(a1l, wlo[1][ks], bh);                                           \
        mfma_p(a2l, wlo[2][ks], bh);                                           \
        mfma_p(a3l, wlo[3][ks], bh);                                           \
        mfma_p(a0c, whi[0][ks], bl);                                           \
        mfma_p(a1c, whi[1][ks], bl);                                           \
        mfma_p(a2c, whi[2][ks], bl);                                           \
        mfma_p(a3c, whi[3][ks], bl);                                           \
      }                                                                        \
    }                                                                          \
    asm volatile("s_nop 7\n\ts_nop 7"                                          \
                 : "+a"(a0h), "+a"(a1h), "+a"(a2h), "+a"(a3h), "+a"(a0l),      \
                   "+a"(a1l), "+a"(a2l), "+a"(a3l), "+a"(a0c), "+a"(a1c),      \
                   "+a"(a2c), "+a"(a3c));                                      \
    /* (5) branch-free 2-step-piped scale: target scaled max 2^7, e<=9 */      \
    float scale_n, inv_n;                                                      \
    {                                                                          \
      int e = 134 - (int)(__float_as_uint(M) >> 23);                           \
      e = e > 9 ? 9 : e;                                                       \
      scale_n = __int_as_float((e + 127) << 23);                               \
      inv_n = __int_as_float((127 - e) << 23);                                 \
    }                                                                          \
    /* (6) elementwise update + per-lane max (accvgpr_read on consumption) */  \
    float am = 0.f;                                                            \
    _Pragma("unroll")                                                          \
    for (int nt = 0; nt < 4; ++nt) {                                           \
      f32x4 av = (nt == 0) ? (a0h + a0l + a0c)                                 \
               : (nt == 1) ? (a1h + a1l + a1c)                                 \
               : (nt == 2) ? (a2h + a2l + a2c)                                 \
                           : (a3h + a3l + a3c);                                \
      _Pragma("unroll")                                                        \
      for (int q = 0; q < 4; ++q) {                                            \
        float ext;                                                             \
        if (w == 0) {                                                          \
          f32x4 ev = (nt == 0) ? E0 : (nt == 1) ? E1 : (nt == 2) ? E2 : E3;    \
          ext = lms * ev[q];                                                   \
        } else if (w == 1) {                                                   \
          ext = vs * ((nt < 2) ? E0[0] : E0[1]);                               \
        } else {                                                               \
          ext = 0.f;                                                           \
        }                                                                      \
        float tot = __builtin_fmaf(av[q], inv_scale, ext);                     \
        float rate = fmaxf(__builtin_fmaf(gain_r[nt][q], tot, bias_r[nt][q]),  \
                           0.f);                                               \
        float sv = s_r[nt][q];                                                 \
        sv = __builtin_fmaf(coef_r[nt][q], rate - sv, sv);                     \
        s_r[nt][q] = sv;                                                       \
        am = fmaxf(am, fabsf(sv));                                             \
      }                                                                        \
    }                                                                          \
    amPrev = am;                                                               \
    /* (7) quantize s_{T+1}, write both k-slice slots of next frags */         \
    half8 h0, h1, l0, l1;                                                      \
    _Pragma("unroll")                                                          \
    for (int j = 0; j < 8; ++j) {                                              \
      float sc0 = s_r[j >> 2][j & 3] * scale_n;                                \
      float sc1 = s_r[2 + (j >> 2)][j & 3] * scale_n;                          \
      _Float16 q0 = (_Float16)sc0;                                             \
      _Float16 q1 = (_Float16)sc1;                                             \
      h0[j] = q0;                                                              \
      l0[j] = (_Float16)(sc0 - (float)q0);                                     \
      h1[j] = q1;                                                              \
      l1[j] = (_Float16)(sc1 - (float)q1);                                     \
    }                                                                          \
    *reinterpret_cast<half8*>(&fragH[CUR ^ 1][wb0]) = h0;                      \
    *reinterpret_cast<half8*>(&fragH[CUR ^ 1][wb1]) = h1;                      \
    *reinterpret_cast<half8*>(&fragL[CUR ^ 1][wb0]) = l0;                      \
    *reinterpret_cast<half8*>(&fragL[CUR ^ 1][wb1]) = l1;                      \
    inv_scale = inv_n;                                                         \
    __syncthreads();                                                           \
  }

#pragma unroll 1
  for (int t = 0; t < TT; t += 2) {
    STEP(t, 0, eA0, eA1, eA2, eA3, eB0, eB1, eB2, eB3)
    STEP(t + 1, 1, eB0, eB1, eB2, eB3, eA0, eA1, eA2, eA3)
  }
#undef STEP

  // Epilogue: epg output = neurons [0,64) -> wave 0
  if (w == 0) {
#pragma unroll
    for (int nt = 0; nt < 4; ++nt) {
      f32x4 o;
#pragma unroll
      for (int q = 0; q < 4; ++q) o[q] = s_r[nt][q];
      *reinterpret_cast<f32x4*>(out + (size_t)br * 64 + nt * 16 + g * 4) = o;
    }
  }
}

extern "C" void kernel_launch(void* const* d_in, const int* in_sizes, int n_in,
                              void* d_out, int out_size, void* d_ws, size_t ws_size,
                              hipStream_t stream) {
  const float* W         = (const float*)d_in[0];
  const float* log_scale = (const float*)d_in[1];
  const float* gain      = (const float*)d_in[2];
  const float* bias      = (const float*)d_in[3];
  const float* log_tau   = (const float*)d_in[4];
  const float* vscale    = (const float*)d_in[5];
  const float* lscale    = (const float*)d_in[6];
  const float* velocity  = (const float*)d_in[7];
  const float* landmarks = (const float*)d_in[8];
  float* out = (float*)d_out;

  ring_attractor_kernel<<<dim3(BB / 16), dim3(256), 0, stream>>>(
      W, log_scale, gain, bias, log_tau, vscale, lscale, velocity, landmarks, out);
}